// Round 1
// baseline (1208.205 us; speedup 1.0000x reference)
//
#include <hip/hip_runtime.h>
#include <hip/hip_bf16.h>
#include <math.h>

#define B 32
#define S 4096
#define H 16
#define QC 1536
#define LORA 512
#define ROPE 64
#define NOPE 128
#define VH 128
#define DM 2048
#define NC 32          // chunks per batch for flash split-K
#define CHUNK (S / NC) // 128 rows per chunk

__device__ __constant__ float SCALE_C = 0.07216878364870323f; // 1/sqrt(192)

// ---------------- Kernel 1: q_t = q_c @ W_UQ  (32x2048), qr = q_c @ W_QR (32x1024)
__global__ void k_proj1(const float* __restrict__ q_c, const float* __restrict__ W_UQ,
                        const float* __restrict__ W_QR, float* __restrict__ q_t,
                        float* __restrict__ qr) {
    __shared__ float qs[QC];
    const int b = blockIdx.y, sl = blockIdx.x, t = threadIdx.x;
    for (int i = t; i < QC / 4; i += 256)
        ((float4*)qs)[i] = ((const float4*)(q_c + (size_t)b * QC))[i];
    __syncthreads();

    const float* W;
    float* out;
    int col0, N;
    if (sl < 8) { W = W_UQ; out = q_t + (size_t)b * 2048; col0 = sl * 256; N = 2048; }
    else        { W = W_QR; out = qr  + (size_t)b * 1024; col0 = (sl - 8) * 256; N = 1024; }
    const int col = col0 + t;
    float acc = 0.f;
    for (int d = 0; d < QC; d += 4) {
        float4 q4 = *(const float4*)(qs + d);
        acc += q4.x * W[(size_t)d * N + col];
        acc += q4.y * W[(size_t)(d + 1) * N + col];
        acc += q4.z * W[(size_t)(d + 2) * N + col];
        acc += q4.w * W[(size_t)(d + 3) * N + col];
    }
    out[col] = acc;
}

// ---------------- Kernel 2: RoPE  (q_pe from qr; kpe_rot from k_pe)
__global__ void k_rope(const float* __restrict__ qr, const float* __restrict__ k_pe,
                       const int* __restrict__ pos_arr, float* __restrict__ q_pe,
                       float* __restrict__ kpe_rot) {
    const int b = blockIdx.x, t = threadIdx.x;
    const int pos = pos_arr[b];
    for (int p = t; p < (H + 1) * 32; p += 256) {
        const int j = p & 31;       // freq index 0..31
        const int grp = p >> 5;     // 0..15 heads, 16 = k_pe
        const double inv = pow(10000.0, -(double)j / 32.0);
        const double f = (double)pos * inv;
        const float c = (float)cos(f), s = (float)sin(f);
        if (grp < H) {
            const float* x = qr + (size_t)b * 1024 + grp * 64;
            float* o = q_pe + (size_t)b * 1024 + grp * 64;
            const float x1 = x[j], x2 = x[j + 32];
            o[j] = x1 * c - x2 * s;
            o[j + 32] = x2 * c + x1 * s;
        } else {
            const float* x = k_pe + (size_t)b * 64;
            float* o = kpe_rot + (size_t)b * 64;
            const float x1 = x[j], x2 = x[j + 32];
            o[j] = x1 * c - x2 * s;
            o[j + 32] = x2 * c + x1 * s;
        }
    }
}

// ---------------- Kernel 3: q_nope[b,h,l] = sum_n q_t[b,h,n] * W_UK[l,h,n]
__global__ void k_qnope(const float* __restrict__ q_t, const float* __restrict__ W_UK,
                        float* __restrict__ q_nope) {
    const int h = blockIdx.x, b = blockIdx.y, t = threadIdx.x;
    __shared__ float qs[NOPE];
    if (t < NOPE) qs[t] = q_t[(size_t)b * 2048 + h * NOPE + t];
    __syncthreads();
    for (int l = t; l < LORA; l += 256) {
        const float* w = W_UK + (size_t)l * (H * NOPE) + h * NOPE;
        float acc = 0.f;
        for (int n = 0; n < NOPE; n += 4) {
            float4 w4 = *(const float4*)(w + n);
            float4 q4 = *(const float4*)(qs + n);
            acc += q4.x * w4.x + q4.y * w4.y + q4.z * w4.z + q4.w * w4.w;
        }
        q_nope[((size_t)b * H + h) * LORA + l] = acc;
    }
}

// ---------------- Kernel 4: flash decode over chunks -> partial (m, l, o)
// Block = 256 threads = 16 groups of 16 lanes; group g owns head g.
// Thread (g,j) holds q elements {4j..4j+3} + 64k (k=0..8; k=8 is the RoPE part)
__global__ __launch_bounds__(256) void k_flash(
    const float* __restrict__ q_nope, const float* __restrict__ q_pe,
    const float* __restrict__ kv_cache, const float* __restrict__ kpe_cache,
    const float* __restrict__ k_c_normed, const float* __restrict__ kpe_rot,
    const int* __restrict__ pos_arr, float* __restrict__ part_o,
    float* __restrict__ part_ml) {
    const int blk = blockIdx.x;
    const int b = blk / NC, c = blk % NC;
    const int t = threadIdx.x;
    const int g = t >> 4, j = t & 15;
    const int pos = pos_arr[b];

    float4 q4[9];
    const float* qn = q_nope + ((size_t)b * H + g) * LORA;
#pragma unroll
    for (int k = 0; k < 8; k++) q4[k] = *(const float4*)(qn + 4 * j + 64 * k);
    q4[8] = *(const float4*)(q_pe + ((size_t)b * H + g) * 64 + 4 * j);

    float m_run = -INFINITY, l_run = 0.f;
    float4 o_acc[8];
#pragma unroll
    for (int k = 0; k < 8; k++) o_acc[k] = make_float4(0.f, 0.f, 0.f, 0.f);

    const int s0 = c * CHUNK;
    for (int st = 0; st < CHUNK; st += 16) {
        float sc[16];
#pragma unroll 4
        for (int r = 0; r < 16; r++) {
            const int s = s0 + st + r;
            const float* kvr = (s == pos) ? (k_c_normed + (size_t)b * LORA)
                                          : (kv_cache + ((size_t)b * S + s) * LORA);
            const float* per = (s == pos) ? (kpe_rot + (size_t)b * 64)
                                          : (kpe_cache + ((size_t)b * S + s) * 64);
            float acc = 0.f;
#pragma unroll
            for (int k = 0; k < 8; k++) {
                float4 kv4 = *(const float4*)(kvr + 4 * j + 64 * k);
                acc += q4[k].x * kv4.x + q4[k].y * kv4.y + q4[k].z * kv4.z + q4[k].w * kv4.w;
            }
            float4 p4 = *(const float4*)(per + 4 * j);
            acc += q4[8].x * p4.x + q4[8].y * p4.y + q4[8].z * p4.z + q4[8].w * p4.w;
            // reduce over the 16 lanes of this group
            acc += __shfl_xor(acc, 8);
            acc += __shfl_xor(acc, 4);
            acc += __shfl_xor(acc, 2);
            acc += __shfl_xor(acc, 1);
            sc[r] = acc * SCALE_C;
        }
        float mt = sc[0];
#pragma unroll
        for (int r = 1; r < 16; r++) mt = fmaxf(mt, sc[r]);
        const float m_new = fmaxf(m_run, mt);
        const float alpha = __expf(m_run - m_new);
        float psum = 0.f;
#pragma unroll
        for (int r = 0; r < 16; r++) { sc[r] = __expf(sc[r] - m_new); psum += sc[r]; }
        l_run = l_run * alpha + psum;
        m_run = m_new;
#pragma unroll
        for (int k = 0; k < 8; k++) {
            o_acc[k].x *= alpha; o_acc[k].y *= alpha;
            o_acc[k].z *= alpha; o_acc[k].w *= alpha;
        }
#pragma unroll 4
        for (int r = 0; r < 16; r++) {
            const int s = s0 + st + r;
            const float* kvr = (s == pos) ? (k_c_normed + (size_t)b * LORA)
                                          : (kv_cache + ((size_t)b * S + s) * LORA);
            const float p = sc[r];
#pragma unroll
            for (int k = 0; k < 8; k++) {
                float4 kv4 = *(const float4*)(kvr + 4 * j + 64 * k);
                o_acc[k].x += p * kv4.x; o_acc[k].y += p * kv4.y;
                o_acc[k].z += p * kv4.z; o_acc[k].w += p * kv4.w;
            }
        }
    }
    float* po = part_o + (((size_t)b * NC + c) * H + g) * LORA;
#pragma unroll
    for (int k = 0; k < 8; k++) *(float4*)(po + 4 * j + 64 * k) = o_acc[k];
    if (j == 0) {
        float* pml = part_ml + (((size_t)b * NC + c) * H + g) * 2;
        pml[0] = m_run;
        pml[1] = l_run;
    }
}

// ---------------- Kernel 5: combine partials -> o (in LDS), fused v = o . W_UV
__global__ void k_combine(const float* __restrict__ part_o, const float* __restrict__ part_ml,
                          const float* __restrict__ W_UV, float* __restrict__ v) {
    const int h = blockIdx.x, b = blockIdx.y, t = threadIdx.x; // 128 threads
    __shared__ float o_s[LORA];
    float m = -INFINITY;
    for (int c = 0; c < NC; c++)
        m = fmaxf(m, part_ml[(((size_t)b * NC + c) * H + h) * 2]);
    float l = 0.f;
    for (int c = 0; c < NC; c++) {
        const float* pml = part_ml + (((size_t)b * NC + c) * H + h) * 2;
        l += pml[1] * __expf(pml[0] - m);
    }
    const float inv_l = 1.0f / l;
    for (int li = t; li < LORA; li += 128) {
        float acc = 0.f;
        for (int c = 0; c < NC; c++) {
            const float scf = __expf(part_ml[(((size_t)b * NC + c) * H + h) * 2] - m);
            acc += part_o[(((size_t)b * NC + c) * H + h) * LORA + li] * scf;
        }
        o_s[li] = acc * inv_l;
    }
    __syncthreads();
    // v[b, h*128 + t] = sum_l o_s[l] * W_UV[l, h, t]
    float acc = 0.f;
    for (int l2 = 0; l2 < LORA; l2++)
        acc += o_s[l2] * W_UV[(size_t)l2 * (H * VH) + h * VH + t];
    v[(size_t)b * (H * VH) + h * VH + t] = acc;
}

// ---------------- Kernel 6: out_part[ks] = V[:, k-slice] @ W_O[k-slice, :]
__global__ void k_out(const float* __restrict__ v, const float* __restrict__ W_O,
                      float* __restrict__ out_part) {
    const int dsl = blockIdx.x, ksl = blockIdx.y, t = threadIdx.x;
    const int d0 = dsl * 128, k0 = ksl * 128;
    __shared__ float vs[32][128];
    for (int i = t; i < 32 * 128; i += 256) {
        const int bi = i >> 7, kk = i & 127;
        vs[bi][kk] = v[(size_t)bi * DM + k0 + kk];
    }
    __syncthreads();
    const int dl = t & 127, bh = t >> 7; // bh = 0/1 -> batches 0..15 / 16..31
    float acc[16];
#pragma unroll
    for (int i = 0; i < 16; i++) acc[i] = 0.f;
    for (int kk = 0; kk < 128; kk++) {
        const float w = W_O[(size_t)(k0 + kk) * DM + d0 + dl];
#pragma unroll
        for (int i = 0; i < 16; i++) acc[i] += vs[bh * 16 + i][kk] * w;
    }
    float* op = out_part + (size_t)ksl * 32 * DM;
#pragma unroll
    for (int i = 0; i < 16; i++) op[(size_t)(bh * 16 + i) * DM + d0 + dl] = acc[i];
}

// ---------------- Kernel 7: reduce the 16 split-K partials
__global__ void k_out_reduce(const float* __restrict__ out_part, float* __restrict__ out) {
    const int idx = blockIdx.x * 256 + threadIdx.x; // 16384 threads * 4 elems
    float4 acc = make_float4(0.f, 0.f, 0.f, 0.f);
    for (int ks = 0; ks < 16; ks++) {
        float4 p = *(const float4*)(out_part + (size_t)ks * (32 * DM) + (size_t)idx * 4);
        acc.x += p.x; acc.y += p.y; acc.z += p.z; acc.w += p.w;
    }
    *(float4*)(out + (size_t)idx * 4) = acc;
}

extern "C" void kernel_launch(void* const* d_in, const int* in_sizes, int n_in,
                              void* d_out, int out_size, void* d_ws, size_t ws_size,
                              hipStream_t stream) {
    const float* q_c        = (const float*)d_in[0];
    const float* k_c_normed = (const float*)d_in[1];
    const float* k_pe       = (const float*)d_in[2];
    const float* kv_c_cache = (const float*)d_in[3];
    const float* k_pe_cache = (const float*)d_in[4];
    const float* W_UQ       = (const float*)d_in[5];
    const float* W_UK       = (const float*)d_in[6];
    const float* W_QR       = (const float*)d_in[7];
    const float* W_UV       = (const float*)d_in[8];
    const float* W_O        = (const float*)d_in[9];
    const int*   pos        = (const int*)d_in[10];

    float* ws = (float*)d_ws;
    float* q_t      = ws;                       // 65536
    float* qr       = q_t + 65536;              // 32768
    float* q_pe     = qr + 32768;               // 32768
    float* kpe_rot  = q_pe + 32768;             // 2048
    float* q_nope   = kpe_rot + 2048;           // 262144
    float* part_o   = q_nope + 262144;          // 32*NC*16*512 = 8388608
    float* part_ml  = part_o + (size_t)B * NC * H * LORA;   // 32768
    float* v        = part_ml + (size_t)B * NC * H * 2;     // 65536
    float* out_part = v + 65536;                // 16*32*2048 = 1048576

    k_proj1<<<dim3(12, 32), 256, 0, stream>>>(q_c, W_UQ, W_QR, q_t, qr);
    k_rope<<<32, 256, 0, stream>>>(qr, k_pe, pos, q_pe, kpe_rot);
    k_qnope<<<dim3(16, 32), 256, 0, stream>>>(q_t, W_UK, q_nope);
    k_flash<<<B * NC, 256, 0, stream>>>(q_nope, q_pe, kv_c_cache, k_pe_cache,
                                        k_c_normed, kpe_rot, pos, part_o, part_ml);
    k_combine<<<dim3(16, 32), 128, 0, stream>>>(part_o, part_ml, W_UV, v);
    k_out<<<dim3(16, 16), 256, 0, stream>>>(v, W_O, out_part);
    k_out_reduce<<<64, 256, 0, stream>>>(out_part, (float*)d_out);
}